// Round 1
// baseline (778.589 us; speedup 1.0000x reference)
//
#include <hip/hip_runtime.h>
#include <math.h>

#define IMW 512
#define IMH 512
#define NPIX (IMW * IMH)
#define TR 16      // output rows per block
#define TCOLS 54   // output cols per block
#define CNT 14     // outputs per phase-2 chunk (4 chunks: 0,14,28,42 .. covers 0..55, mask >=54)
#define C1F 1.0e-4f
#define C2F 9.0e-4f

struct Weights { float w[11]; };

__global__ __launch_bounds__(64)
void ssim_l1_kernel(const float* __restrict__ warped,
                    const float* __restrict__ target,
                    double* __restrict__ accum,   // [0]=l1 sum, [1]=ssim sum
                    Weights wt)
{
    // V[quantity][local col 0..65][row 0..15], row stride 17 (pad) -> <=2-way LDS conflicts
    __shared__ float V[5][66][TR + 1];

    const int L     = threadIdx.x;     // 0..63
    const int bx    = blockIdx.x;      // 0..9
    const int by    = blockIdx.y;      // 0..31
    const int plane = blockIdx.z;      // 0..95

    const int c0  = bx * TCOLS;
    const int r0  = by * TR;
    const int col = c0 - 5 + L;                      // global column this lane loads
    const bool colOK = (col >= 0) && (col < IMW);
    const bool l1ok  = (L >= 5) && (L < 59) && (col < IMW);  // col>=0 implied by L>=5

    const size_t base = (size_t)plane * NPIX;
    const float* xp = warped + base + col;
    const float* yp = target + base + col;

    // sliding 11-row windows for x, y, x^2, y^2, xy (static indexing via full unroll)
    float wa[11], wb[11], wa2[11], wb2[11], wab[11];
    float l1sum = 0.0f;

    #pragma unroll
    for (int i = 0; i < TR + 10; ++i) {
        const int rr = r0 - 5 + i;
        const bool ok = colOK && (rr >= 0) && (rr < IMH);
        float x = 0.0f, y = 0.0f;
        if (ok) {
            x = xp[(size_t)rr * IMW];
            y = yp[(size_t)rr * IMW];
        }
        const int slot = i % 11;
        wa[slot]  = x;      wb[slot]  = y;
        wa2[slot] = x * x;  wb2[slot] = y * y;  wab[slot] = x * y;

        // L1 term: rows r0..r0+15 <-> i in [5,20]; cols c0..c0+53 <-> lanes 5..58
        if (l1ok && i >= 5 && i <= 20) l1sum += fabsf(x - y);

        if (i >= 10) {
            const int tt = i - 10;   // V row index 0..15, image row r0+tt (window center r0+tt)
            float mu1 = 0.f, mu2 = 0.f, m20 = 0.f, m02 = 0.f, m11 = 0.f;
            #pragma unroll
            for (int k = 0; k < 11; ++k) {
                const int s = (tt + k) % 11;   // static after unroll
                const float wk = wt.w[k];
                mu1 = fmaf(wk, wa[s],  mu1);
                mu2 = fmaf(wk, wb[s],  mu2);
                m20 = fmaf(wk, wa2[s], m20);
                m02 = fmaf(wk, wb2[s], m02);
                m11 = fmaf(wk, wab[s], m11);
            }
            V[0][L][tt] = mu1;
            V[1][L][tt] = mu2;
            V[2][L][tt] = m20;
            V[3][L][tt] = m02;
            V[4][L][tt] = m11;
            if (L < 2) {   // zero-fill pad columns 64,65 (read by chunk 3, outputs masked)
                V[0][64 + L][tt] = 0.f;
                V[1][64 + L][tt] = 0.f;
                V[2][64 + L][tt] = 0.f;
                V[3][64 + L][tt] = 0.f;
                V[4][64 + L][tt] = 0.f;
            }
        }
    }

    __syncthreads();

    // ---- phase 2: horizontal blur (register sliding, scatter form) + SSIM map ----
    const int t     = L & 15;        // row within tile
    const int j     = L >> 4;        // column chunk
    const int start = j * CNT;       // 0,14,28,42

    float acc0[CNT], acc1[CNT], acc2[CNT], acc3[CNT], acc4[CNT];
    #pragma unroll
    for (int m = 0; m < CNT; ++m) {
        acc0[m] = 0.f; acc1[m] = 0.f; acc2[m] = 0.f; acc3[m] = 0.f; acc4[m] = 0.f;
    }

    #pragma unroll
    for (int s = 0; s < CNT + 10; ++s) {
        const int cs = start + s;            // <= 65
        const float v0 = V[0][cs][t];
        const float v1 = V[1][cs][t];
        const float v2 = V[2][cs][t];
        const float v3 = V[3][cs][t];
        const float v4 = V[4][cs][t];
        #pragma unroll
        for (int m = 0; m < CNT; ++m) {
            if (m <= s && (s - m) <= 10) {   // statically folded
                const float wk = wt.w[s - m];
                acc0[m] = fmaf(wk, v0, acc0[m]);
                acc1[m] = fmaf(wk, v1, acc1[m]);
                acc2[m] = fmaf(wk, v2, acc2[m]);
                acc3[m] = fmaf(wk, v3, acc3[m]);
                acc4[m] = fmaf(wk, v4, acc4[m]);
            }
        }
    }

    float ssum = 0.0f;
    #pragma unroll
    for (int m = 0; m < CNT; ++m) {
        const int o  = start + m;       // local output col
        const int gc = c0 + o;          // global output col
        if (o < TCOLS && gc < IMW) {
            const float mu1 = acc0[m], mu2 = acc1[m];
            const float mu1sq = mu1 * mu1;
            const float mu2sq = mu2 * mu2;
            const float mu12  = mu1 * mu2;
            const float s1  = acc2[m] - mu1sq;
            const float s2  = acc3[m] - mu2sq;
            const float s12 = acc4[m] - mu12;
            const float num = (2.0f * mu12 + C1F) * (2.0f * s12 + C2F);
            const float den = (mu1sq + mu2sq + C1F) * (s1 + s2 + C2F);
            ssum += num / den;
        }
    }

    // wave reduction (single-wave block)
    #pragma unroll
    for (int off = 32; off > 0; off >>= 1) {
        l1sum += __shfl_down(l1sum, off);
        ssum  += __shfl_down(ssum,  off);
    }
    if (L == 0) {
        atomicAdd(&accum[0], (double)l1sum);
        atomicAdd(&accum[1], (double)ssum);
    }
}

__global__ void finalize_kernel(const double* __restrict__ accum,
                                float* __restrict__ out)
{
    const double n = 25165824.0;   // 32*3*512*512
    const double l1   = accum[0] / n;
    const double ssim = accum[1] / n;
    out[0] = (float)(0.5 * l1 + 0.5 * (1.0 - ssim));
}

extern "C" void kernel_launch(void* const* d_in, const int* in_sizes, int n_in,
                              void* d_out, int out_size, void* d_ws, size_t ws_size,
                              hipStream_t stream)
{
    const float* warped = (const float*)d_in[0];
    const float* target = (const float*)d_in[1];
    float* out    = (float*)d_out;
    double* accum = (double*)d_ws;

    hipMemsetAsync(d_ws, 0, 2 * sizeof(double), stream);

    // Gaussian window, computed in f32 exactly like the reference
    Weights wt;
    float g[11], sum = 0.0f;
    for (int i = 0; i < 11; ++i) {
        const float c = (float)(i - 5);
        g[i] = expf(-(c * c) / (2.0f * 1.5f * 1.5f));
        sum += g[i];
    }
    for (int i = 0; i < 11; ++i) wt.w[i] = g[i] / sum;

    dim3 grid(10, 32, 96);   // x-tiles (54 cols), y-tiles (16 rows), B*C planes
    dim3 block(64);
    hipLaunchKernelGGL(ssim_l1_kernel, grid, block, 0, stream,
                       warped, target, accum, wt);
    hipLaunchKernelGGL(finalize_kernel, dim3(1), dim3(1), 0, stream, accum, out);
}

// Round 2
// 276.584 us; speedup vs baseline: 2.8150x; 2.8150x over previous
//
#include <hip/hip_runtime.h>
#include <math.h>

#define IMW 512
#define IMH 512
#define NPIX (IMW * IMH)
#define TR 16      // output rows per wave
#define TCOLS 54   // output cols per wave (lanes 5..58)
#define C1F 1.0e-4f
#define C2F 9.0e-4f
#define NBLK (10 * 8 * 96)

struct Weights { float w[11]; };

__global__ __launch_bounds__(256)
void ssim_l1_kernel(const float* __restrict__ warped,
                    const float* __restrict__ target,
                    float2* __restrict__ partial,
                    Weights wt)
{
    const int lane = threadIdx.x & 63;
    const int wv   = threadIdx.x >> 6;     // wave 0..3: row-strip within y-group
    const int bx    = blockIdx.x;          // 0..9
    const int by    = blockIdx.y;          // 0..7
    const int plane = blockIdx.z;          // 0..95

    const int c0  = bx * TCOLS;
    const int r0  = (by * 4 + wv) * TR;
    const int col = c0 - 5 + lane;                    // global column this lane owns
    const bool colOK = (col >= 0) && (col < IMW);
    const bool valid = (lane >= 5) && (lane < 59) && (col < IMW); // col>=0 implied

    const size_t base = (size_t)plane * NPIX;
    const float* xp = warped + base + col;
    const float* yp = target + base + col;

    // sliding 11-row windows (static indexing via full unroll)
    float wa[11], wb[11], wa2[11], wb2[11], wab[11];
    float l1sum = 0.0f, ssum = 0.0f;

    #pragma unroll
    for (int i = 0; i < TR + 10; ++i) {
        const int rr = r0 - 5 + i;
        const bool ok = colOK && (rr >= 0) && (rr < IMH);
        float x = 0.0f, y = 0.0f;
        if (ok) {
            x = xp[(size_t)rr * IMW];
            y = yp[(size_t)rr * IMW];
        }
        const int slot = i % 11;
        wa[slot]  = x;      wb[slot]  = y;
        wa2[slot] = x * x;  wb2[slot] = y * y;  wab[slot] = x * y;

        if (i >= 10) {
            const int tt = i - 10;            // center row = r0 + tt
            // ---- vertical blur (registers) ----
            float v0 = 0.f, v1 = 0.f, v2 = 0.f, v3 = 0.f, v4 = 0.f;
            #pragma unroll
            for (int k = 0; k < 11; ++k) {
                const int s = (tt + k) % 11;  // static after unroll
                const float wk = wt.w[k];
                v0 = fmaf(wk, wa[s],  v0);
                v1 = fmaf(wk, wb[s],  v1);
                v2 = fmaf(wk, wa2[s], v2);
                v3 = fmaf(wk, wb2[s], v3);
                v4 = fmaf(wk, wab[s], v4);
            }
            // ---- horizontal blur via cross-lane shuffle ----
            const float w5 = wt.w[5];
            float h0 = w5 * v0, h1 = w5 * v1, h2 = w5 * v2, h3 = w5 * v3, h4 = w5 * v4;
            #pragma unroll
            for (int k = 0; k < 11; ++k) {
                if (k == 5) continue;
                const int src = lane + k - 5;   // in [0,63] for valid output lanes
                const float wk = wt.w[k];
                h0 = fmaf(wk, __shfl(v0, src), h0);
                h1 = fmaf(wk, __shfl(v1, src), h1);
                h2 = fmaf(wk, __shfl(v2, src), h2);
                h3 = fmaf(wk, __shfl(v3, src), h3);
                h4 = fmaf(wk, __shfl(v4, src), h4);
            }
            if (valid) {
                // L1 at the center row: value loaded at iteration i-5
                const int s5 = (i - 5) % 11;    // static after unroll
                l1sum += fabsf(wa[s5] - wb[s5]);
                // SSIM map
                const float mu1 = h0, mu2 = h1;
                const float mu1sq = mu1 * mu1;
                const float mu2sq = mu2 * mu2;
                const float mu12  = mu1 * mu2;
                const float s1  = h2 - mu1sq;
                const float s2  = h3 - mu2sq;
                const float s12 = h4 - mu12;
                const float num = (2.0f * mu12 + C1F) * (2.0f * s12 + C2F);
                const float den = (mu1sq + mu2sq + C1F) * (s1 + s2 + C2F);
                ssum += num / den;
            }
        }
    }

    // ---- wave reduction ----
    #pragma unroll
    for (int off = 32; off > 0; off >>= 1) {
        l1sum += __shfl_down(l1sum, off);
        ssum  += __shfl_down(ssum,  off);
    }

    // ---- block reduction (tiny LDS, one write per block; no global atomics) ----
    __shared__ float red[8];
    if (lane == 0) { red[wv] = l1sum; red[4 + wv] = ssum; }
    __syncthreads();
    if (threadIdx.x == 0) {
        const float L1 = red[0] + red[1] + red[2] + red[3];
        const float SS = red[4] + red[5] + red[6] + red[7];
        const int bid = (blockIdx.z * gridDim.y + blockIdx.y) * gridDim.x + blockIdx.x;
        partial[bid] = make_float2(L1, SS);
    }
}

__global__ __launch_bounds__(256)
void reduce_kernel(const float2* __restrict__ partial, float* __restrict__ out)
{
    double l1 = 0.0, ss = 0.0;
    for (int i = threadIdx.x; i < NBLK; i += 256) {
        const float2 p = partial[i];
        l1 += (double)p.x;
        ss += (double)p.y;
    }
    #pragma unroll
    for (int off = 32; off > 0; off >>= 1) {
        l1 += __shfl_down(l1, off);
        ss += __shfl_down(ss, off);
    }
    __shared__ double red[8];
    const int wv = threadIdx.x >> 6, lane = threadIdx.x & 63;
    if (lane == 0) { red[wv] = l1; red[4 + wv] = ss; }
    __syncthreads();
    if (threadIdx.x == 0) {
        const double n = 25165824.0;   // 32*3*512*512
        const double L1 = (red[0] + red[1] + red[2] + red[3]) / n;
        const double SS = (red[4] + red[5] + red[6] + red[7]) / n;
        out[0] = (float)(0.5 * L1 + 0.5 * (1.0 - SS));
    }
}

extern "C" void kernel_launch(void* const* d_in, const int* in_sizes, int n_in,
                              void* d_out, int out_size, void* d_ws, size_t ws_size,
                              hipStream_t stream)
{
    const float* warped = (const float*)d_in[0];
    const float* target = (const float*)d_in[1];
    float* out      = (float*)d_out;
    float2* partial = (float2*)d_ws;

    // Gaussian window (f32, same as reference)
    Weights wt;
    float g[11], sum = 0.0f;
    for (int i = 0; i < 11; ++i) {
        const float c = (float)(i - 5);
        g[i] = expf(-(c * c) / (2.0f * 1.5f * 1.5f));
        sum += g[i];
    }
    for (int i = 0; i < 11; ++i) wt.w[i] = g[i] / sum;

    dim3 grid(10, 8, 96);   // x-tiles(54 cols) × y-groups(4 waves × 16 rows) × planes
    dim3 block(256);
    hipLaunchKernelGGL(ssim_l1_kernel, grid, block, 0, stream,
                       warped, target, partial, wt);
    hipLaunchKernelGGL(reduce_kernel, dim3(1), dim3(256), 0, stream, partial, out);
}